// Round 1
// baseline (653.995 us; speedup 1.0000x reference)
//
#include <hip/hip_runtime.h>

#define B 16

// ---------------- 3-NN + inverse-distance weights ----------------
// xyzF: [B,N,3] fine, xyzC: [B,S,3] coarse.
// Writes idx_out[b*N+n] = 3 nearest coarse indices, w_out = normalized weights.
__global__ __launch_bounds__(256) void knn3_kernel(
    const float* __restrict__ xyzF, const float* __restrict__ xyzC,
    int N, int S, int4* __restrict__ idx_out, float4* __restrict__ w_out) {
    extern __shared__ float lds[];  // [S][4]: x,y,z,|b|^2
    const int b = blockIdx.y;
    const float* cbase = xyzC + (size_t)b * S * 3;
    for (int j = threadIdx.x; j < S; j += blockDim.x) {
        float x = cbase[j * 3 + 0], y = cbase[j * 3 + 1], z = cbase[j * 3 + 2];
        lds[j * 4 + 0] = x; lds[j * 4 + 1] = y; lds[j * 4 + 2] = z;
        lds[j * 4 + 3] = x * x + y * y + z * z;
    }
    __syncthreads();
    const int n = blockIdx.x * blockDim.x + threadIdx.x;
    if (n >= N) return;
    const float* fp = xyzF + ((size_t)b * N + n) * 3;
    const float ax = fp[0], ay = fp[1], az = fp[2];
    const float an2 = ax * ax + ay * ay + az * az;
    float d0 = 1e30f, d1 = 1e30f, d2 = 1e30f;
    int i0 = 0, i1 = 0, i2 = 0;
#pragma unroll 4
    for (int j = 0; j < S; ++j) {
        // same formula as reference: |a|^2 + |b|^2 - 2 a.b  (broadcast LDS reads)
        float bx = lds[j * 4 + 0], by = lds[j * 4 + 1];
        float bz = lds[j * 4 + 2], bn2 = lds[j * 4 + 3];
        float dot = ax * bx + ay * by + az * bz;
        float d = an2 + bn2 - 2.0f * dot;
        if (d < d2) {
            if (d < d1) {
                d2 = d1; i2 = i1;
                if (d < d0) { d1 = d0; i1 = i0; d0 = d; i0 = j; }
                else        { d1 = d;  i1 = j; }
            } else { d2 = d; i2 = j; }
        }
    }
    float w0 = 1.0f / (d0 + 1e-8f);
    float w1 = 1.0f / (d1 + 1e-8f);
    float w2 = 1.0f / (d2 + 1e-8f);
    float inv = 1.0f / (w0 + w1 + w2);
    size_t o = (size_t)b * N + n;
    idx_out[o] = make_int4(i0, i1, i2, 0);
    w_out[o] = make_float4(w0 * inv, w1 * inv, w2 * inv, 0.0f);
}

// ---------------- skip-channel copy (channels [0,C1) of out) ----------------
// skip: [B,C1,N] -> out[b, 0..C1, :] ; per-batch contiguous block, float4.
__global__ __launch_bounds__(256) void copy_skip_kernel(
    const float4* __restrict__ skip, float4* __restrict__ out,
    int logPerB, int outStride4, int total4) {
    int i = blockIdx.x * blockDim.x + threadIdx.x;
    if (i >= total4) return;
    int b = i >> logPerB;
    int r = i & ((1 << logPerB) - 1);
    out[(size_t)b * outStride4 + r] = skip[i];
}

// ---------------- interpolation (channels [C1, C1+C2) of out) ----------------
// prev: [B,C2,S]; out[b, C1+c, n] = sum_k w[b,n,k] * prev[b, c, idx[b,n,k]]
// Block: (n-chunk, channel-chunk of CH, batch). CH rows staged in LDS.
template <int CH>
__global__ __launch_bounds__(256) void interp_kernel(
    const float* __restrict__ prev, const int4* __restrict__ idx,
    const float4* __restrict__ w, float* __restrict__ out,
    int N, int S, int C1, int C2, int logNW) {
    extern __shared__ float lds[];  // CH * S floats
    const int b = blockIdx.z;
    const int c0 = blockIdx.y * CH;
    // stage CH contiguous rows of prev into LDS (contiguous -> float4 copy)
    {
        const float4* src = reinterpret_cast<const float4*>(
            prev + ((size_t)b * C2 + c0) * S);
        float4* dst = reinterpret_cast<float4*>(lds);
        const int cnt = CH * S / 4;
        for (int j = threadIdx.x; j < cnt; j += 256) dst[j] = src[j];
    }
    __syncthreads();
    const int t = threadIdx.x;
    const int nw = 1 << logNW;              // min(N,256)
    const int n = blockIdx.x * nw + (t & (nw - 1));
    const int cstart = t >> logNW;          // 0 when N>=256
    const int cstep = 256 >> logNW;         // 1 when N>=256
    const size_t o = (size_t)b * N + n;
    const int4 id = idx[o];
    const float4 ww = w[o];
    float* outbase = out + ((size_t)b * (C1 + C2) + C1 + c0) * N + n;
#pragma unroll
    for (int c = cstart; c < CH; c += cstep) {
        const float* row = lds + c * S;
        float v = fmaf(ww.x, row[id.x], fmaf(ww.y, row[id.y], ww.z * row[id.z]));
        outbase[(size_t)c * N] = v;
    }
}

static inline int ilog2(int x) { return 31 - __builtin_clz((unsigned)x); }

static void run_stage(const float* xyzF, const float* xyzC,
                      const float* skip, const float* prev, float* out,
                      int N, int S, int C1, int C2,
                      int4* idxbuf, float4* wbuf, hipStream_t stream) {
    // 1) 3-NN
    dim3 kgrid((N + 255) / 256, B);
    knn3_kernel<<<kgrid, 256, S * 4 * sizeof(float), stream>>>(
        xyzF, xyzC, N, S, idxbuf, wbuf);
    // 2) skip copy
    int perB4 = C1 * N / 4;                  // power of two for all stages
    int total4 = B * perB4;
    copy_skip_kernel<<<(total4 + 255) / 256, 256, 0, stream>>>(
        reinterpret_cast<const float4*>(skip), reinterpret_cast<float4*>(out),
        ilog2(perB4), (C1 + C2) * N / 4, total4);
    // 3) interpolate
    const int CH = 8;
    int logNW = (N >= 256) ? 8 : ilog2(N);
    dim3 igrid((N >= 256) ? N / 256 : 1, C2 / CH, B);
    interp_kernel<CH><<<igrid, 256, CH * S * sizeof(float), stream>>>(
        prev, idxbuf, wbuf, out, N, S, C1, C2, logNW);
}

extern "C" void kernel_launch(void* const* d_in, const int* in_sizes, int n_in,
                              void* d_out, int out_size, void* d_ws, size_t ws_size,
                              hipStream_t stream) {
    // Identify inputs by flat size (all 10 sizes are distinct).
    static const int xyzSz[5] = {16 * 4096 * 3, 16 * 1024 * 3, 16 * 256 * 3,
                                 16 * 64 * 3, 16 * 16 * 3};
    static const int fSz[5] = {16 * 64 * 4096, 16 * 128 * 1024, 16 * 256 * 256,
                               16 * 512 * 64, 16 * 1024 * 16};
    const float* xyz[5] = {nullptr, nullptr, nullptr, nullptr, nullptr};
    const float* f[5] = {nullptr, nullptr, nullptr, nullptr, nullptr};
    for (int i = 0; i < n_in; ++i) {
        for (int j = 0; j < 5; ++j) {
            if (in_sizes[i] == xyzSz[j] && !xyz[j]) { xyz[j] = (const float*)d_in[i]; goto next; }
            if (in_sizes[i] == fSz[j] && !f[j])     { f[j] = (const float*)d_in[i];  goto next; }
        }
    next:;
    }

    char* ws = (char*)d_ws;
    int4* idxbuf = (int4*)(ws);                       // 16*4096*16 = 1 MiB
    float4* wbuf = (float4*)(ws + (1u << 20));        // 1 MiB
    float* x1 = (float*)(ws + (2u << 20));            // 16*1536*64  = 6.29 MB
    float* x2 = (float*)(ws + (2u << 20) + 6291456u); // 16*1792*256 = 29.36 MB
    float* x3 = (float*)(ws + (2u << 20) + 6291456u + 29360128u); // 125.8 MB

    // stage 0: coarse 16 -> fine 64;   out x1 [16, 512+1024, 64]
    run_stage(xyz[3], xyz[4], f[3], f[4], x1, 64, 16, 512, 1024, idxbuf, wbuf, stream);
    // stage 1: coarse 64 -> fine 256;  out x2 [16, 256+1536, 256]
    run_stage(xyz[2], xyz[3], f[2], x1, x2, 256, 64, 256, 1536, idxbuf, wbuf, stream);
    // stage 2: coarse 256 -> fine 1024; out x3 [16, 128+1792, 1024]
    run_stage(xyz[1], xyz[2], f[1], x2, x3, 1024, 256, 128, 1792, idxbuf, wbuf, stream);
    // stage 3: coarse 1024 -> fine 4096; out d_out [16, 64+1920, 4096]
    run_stage(xyz[0], xyz[1], f[0], x3, (float*)d_out, 4096, 1024, 64, 1920,
              idxbuf, wbuf, stream);
}

// Round 2
// 269.291 us; speedup vs baseline: 2.4286x; 2.4286x over previous
//
#include <hip/hip_runtime.h>

#define B 16
typedef float f32x4 __attribute__((ext_vector_type(4)));

static inline int ilog2i(int x) { return 31 - __builtin_clz((unsigned)x); }

// ---------------- 3-NN + inverse-distance weights ----------------
// 4 threads cooperate per fine point: each scans S/4 coarse points (segment-
// padded LDS), then 2-round shfl_xor merge of top-3 lists with (d, idx)
// tie-break (matches jax.lax.top_k lowest-index-on-tie).
__global__ __launch_bounds__(256) void knn3_kernel(
    const float* __restrict__ xyzF, const float* __restrict__ xyzC,
    int N, int S, int logS4, int4* __restrict__ idx_out, float4* __restrict__ w_out) {
    extern __shared__ float lds[];  // 4 segments x (S/4 + 1) x {x,y,z,|b|^2}
    const int b = blockIdx.y;
    const int S4 = S >> 2;
    const float* cbase = xyzC + (size_t)b * S * 3;
    for (int j = threadIdx.x; j < S; j += 256) {
        float x = cbase[j * 3 + 0], y = cbase[j * 3 + 1], z = cbase[j * 3 + 2];
        int seg = j >> logS4, jj = j & (S4 - 1);
        float* p = lds + (size_t)(seg * (S4 + 1) + jj) * 4;
        p[0] = x; p[1] = y; p[2] = z; p[3] = x * x + y * y + z * z;
    }
    __syncthreads();
    const int t = threadIdx.x;
    const int sub = t & 3;
    const int n = blockIdx.x * 64 + (t >> 2);
    if (n >= N) return;
    const float* fp = xyzF + ((size_t)b * N + n) * 3;
    const float ax = fp[0], ay = fp[1], az = fp[2];
    const float an2 = ax * ax + ay * ay + az * az;
    float d0 = 1e30f, d1 = 1e30f, d2 = 1e30f;
    int i0 = -1, i1 = -1, i2 = -1;
    const f32x4* seg4 = reinterpret_cast<const f32x4*>(lds) + sub * (S4 + 1);
    const int jbase = sub * S4;
    for (int k = 0; k < S4; ++k) {
        f32x4 c = seg4[k];
        float d = an2 + c.w - 2.0f * (ax * c.x + ay * c.y + az * c.z);
        int j = jbase + k;
        if (d < d2) {  // ascending j: strict < keeps earliest index on ties
            if (d < d1) {
                d2 = d1; i2 = i1;
                if (d < d0) { d1 = d0; i1 = i0; d0 = d; i0 = j; }
                else        { d1 = d;  i1 = j; }
            } else { d2 = d; i2 = j; }
        }
    }
    // merge top-3 lists across the 4 sub-lanes (butterfly)
#pragma unroll
    for (int r = 1; r <= 2; r <<= 1) {
        float e0 = __shfl_xor(d0, r), e1 = __shfl_xor(d1, r), e2 = __shfl_xor(d2, r);
        int   j0 = __shfl_xor(i0, r), j1 = __shfl_xor(i1, r), j2 = __shfl_xor(i2, r);
        float ed[3] = {e0, e1, e2};
        int   ej[3] = {j0, j1, j2};
#pragma unroll
        for (int m = 0; m < 3; ++m) {
            float d = ed[m]; int j = ej[m];
            if (d < d0 || (d == d0 && j < i0)) {
                d2 = d1; i2 = i1; d1 = d0; i1 = i0; d0 = d; i0 = j;
            } else if (d < d1 || (d == d1 && j < i1)) {
                d2 = d1; i2 = i1; d1 = d; i1 = j;
            } else if (d < d2 || (d == d2 && j < i2)) {
                d2 = d; i2 = j;
            }
        }
    }
    if (sub == 0) {
        float w0 = 1.0f / (d0 + 1e-8f);
        float w1 = 1.0f / (d1 + 1e-8f);
        float w2 = 1.0f / (d2 + 1e-8f);
        float inv = 1.0f / (w0 + w1 + w2);
        size_t o = (size_t)b * N + n;
        idx_out[o] = make_int4(i0, i1, i2, 0);
        w_out[o] = make_float4(w0 * inv, w1 * inv, w2 * inv, 0.0f);
    }
}

// ---------------- skip-channel copy (channels [0,C1) of out) ----------------
__global__ __launch_bounds__(256) void copy_skip_kernel(
    const float4* __restrict__ skip, float4* __restrict__ out,
    int logPerB, int outStride4, int total4) {
    int i = blockIdx.x * blockDim.x + threadIdx.x;
    if (i >= total4) return;
    int b = i >> logPerB;
    int r = i & ((1 << logPerB) - 1);
    out[(size_t)b * outStride4 + r] = skip[i];
}

// ---------------- interpolation (channels [C1, C1+C2) of out) ----------------
// Block = (c-chunk of CH, batch). Stage CH rows ONCE as 4-channel float4
// planes lds[plane][S], loop all n internally. Thread handles 4 consecutive
// n x (CH/CL) channels; b128 gathers (4 ch/read), float4 stores along n.
template <int CH, int NT4>
__global__ __launch_bounds__(256) void interp_kernel(
    const float* __restrict__ prev, const int4* __restrict__ idx,
    const f32x4* __restrict__ w, float* __restrict__ out,
    int N, int S, int logS, int C1, int C2) {
    constexpr int CL = 256 / NT4;        // channel-lanes
    constexpr int PP = CH / (4 * CL);    // float4 planes per thread
    extern __shared__ f32x4 lds4[];      // (CH/4) planes x S
    float* ldsf = reinterpret_cast<float*>(lds4);
    const int b = blockIdx.x;
    const int c0 = blockIdx.y * CH;
    const int S4 = S >> 2;
    // stage CH rows, repacking row-major -> [plane][point][4ch]
    {
        const f32x4* src = reinterpret_cast<const f32x4*>(prev + ((size_t)b * C2 + c0) * S);
        for (int e = threadIdx.x; e < CH * S4; e += 256) {
            int c = e >> (logS - 2);
            int s4 = e & (S4 - 1);
            f32x4 v = src[(size_t)c * S4 + s4];
            int base = (((c >> 2) * S + s4 * 4) << 2) + (c & 3);
            ldsf[base + 0] = v[0];
            ldsf[base + 4] = v[1];
            ldsf[base + 8] = v[2];
            ldsf[base + 12] = v[3];
        }
    }
    __syncthreads();
    const int tn = threadIdx.x & (NT4 - 1);
    const int tc = threadIdx.x / NT4;
    const int iters = N / (NT4 * 4);
    float* outb = out + ((size_t)b * (C1 + C2) + C1 + c0) * N;
    for (int it = 0; it < iters; ++it) {
        const int n0 = (it * NT4 + tn) * 4;
        const size_t o = (size_t)b * N + n0;
        int4 id[4]; f32x4 ww[4];
#pragma unroll
        for (int q = 0; q < 4; ++q) { id[q] = idx[o + q]; ww[q] = w[o + q]; }
#pragma unroll
        for (int pp = 0; pp < PP; ++pp) {
            const int plane = tc * PP + pp;
            const f32x4* pl = lds4 + (size_t)plane * S;
            f32x4 v[4];
#pragma unroll
            for (int q = 0; q < 4; ++q) {
                f32x4 g0 = pl[id[q].x];
                f32x4 g1 = pl[id[q].y];
                f32x4 g2 = pl[id[q].z];
                v[q] = ww[q][0] * g0 + ww[q][1] * g1 + ww[q][2] * g2;
            }
            float* ob = outb + (size_t)(plane * 4) * N + n0;
#pragma unroll
            for (int j = 0; j < 4; ++j) {
                f32x4 st = {v[0][j], v[1][j], v[2][j], v[3][j]};
                *reinterpret_cast<f32x4*>(ob + (size_t)j * N) = st;
            }
        }
    }
}

template <int CH, int NT4>
static void run_stage(const float* xyzF, const float* xyzC,
                      const float* skip, const float* prev, float* out,
                      int N, int S, int C1, int C2,
                      int4* idxbuf, float4* wbuf, hipStream_t stream) {
    // 1) 3-NN
    knn3_kernel<<<dim3(N / 64, B), 256, (size_t)(S + 4) * 16, stream>>>(
        xyzF, xyzC, N, S, ilog2i(S / 4), idxbuf, wbuf);
    // 2) skip copy
    int perB4 = C1 * N / 4;  // power of two for all stages
    int total4 = B * perB4;
    copy_skip_kernel<<<(total4 + 255) / 256, 256, 0, stream>>>(
        reinterpret_cast<const float4*>(skip), reinterpret_cast<float4*>(out),
        ilog2i(perB4), (C1 + C2) * N / 4, total4);
    // 3) interpolate: grid (batch, c-chunks); n-loop internal
    interp_kernel<CH, NT4><<<dim3(B, C2 / CH), 256, (size_t)CH * S * 4, stream>>>(
        prev, idxbuf, reinterpret_cast<const f32x4*>(wbuf), out, N, S, ilog2i(S), C1, C2);
}

extern "C" void kernel_launch(void* const* d_in, const int* in_sizes, int n_in,
                              void* d_out, int out_size, void* d_ws, size_t ws_size,
                              hipStream_t stream) {
    static const int xyzSz[5] = {16 * 4096 * 3, 16 * 1024 * 3, 16 * 256 * 3,
                                 16 * 64 * 3, 16 * 16 * 3};
    static const int fSz[5] = {16 * 64 * 4096, 16 * 128 * 1024, 16 * 256 * 256,
                               16 * 512 * 64, 16 * 1024 * 16};
    const float* xyz[5] = {nullptr, nullptr, nullptr, nullptr, nullptr};
    const float* f[5] = {nullptr, nullptr, nullptr, nullptr, nullptr};
    for (int i = 0; i < n_in; ++i) {
        for (int j = 0; j < 5; ++j) {
            if (in_sizes[i] == xyzSz[j] && !xyz[j]) { xyz[j] = (const float*)d_in[i]; goto next; }
            if (in_sizes[i] == fSz[j] && !f[j])     { f[j] = (const float*)d_in[i];  goto next; }
        }
    next:;
    }

    char* ws = (char*)d_ws;
    int4* idxbuf = (int4*)(ws);                       // 1 MiB
    float4* wbuf = (float4*)(ws + (1u << 20));        // 1 MiB
    float* x1 = (float*)(ws + (2u << 20));            // 16*1536*64  = 6.29 MB
    float* x2 = (float*)(ws + (2u << 20) + 6291456u); // 16*1792*256 = 29.36 MB
    float* x3 = (float*)(ws + (2u << 20) + 6291456u + 29360128u); // 125.8 MB

    // stage 0: coarse 16 -> fine 64;    x1 [16, 512+1024, 64]
    run_stage<64, 16>(xyz[3], xyz[4], f[3], f[4], x1, 64, 16, 512, 1024, idxbuf, wbuf, stream);
    // stage 1: coarse 64 -> fine 256;   x2 [16, 256+1536, 256]
    run_stage<16, 64>(xyz[2], xyz[3], f[2], x1, x2, 256, 64, 256, 1536, idxbuf, wbuf, stream);
    // stage 2: coarse 256 -> fine 1024; x3 [16, 128+1792, 1024]
    run_stage<8, 256>(xyz[1], xyz[2], f[1], x2, x3, 1024, 256, 128, 1792, idxbuf, wbuf, stream);
    // stage 3: coarse 1024 -> fine 4096; d_out [16, 64+1920, 4096]
    run_stage<8, 256>(xyz[0], xyz[1], f[0], x3, (float*)d_out, 4096, 1024, 64, 1920,
                      idxbuf, wbuf, stream);
}

// Round 3
// 150.641 us; speedup vs baseline: 4.3414x; 1.7876x over previous
//
#include <hip/hip_runtime.h>

#define B 16
typedef float f32x4 __attribute__((ext_vector_type(4)));

// ===================== fused 4-stage 3-NN =====================
// 4 threads per fine point; segment-padded LDS scan + shfl_xor top-3 merge
// with (d, idx) tie-break (matches jax.lax.top_k lowest-index-on-tie).
// Stage block ranges: s3 [0,1024), s2 [1024,1280), s1 [1280,1344), s0 [1344,1360).
__global__ __launch_bounds__(256) void knn_all_kernel(
    const float* __restrict__ xyz0, const float* __restrict__ xyz1,
    const float* __restrict__ xyz2, const float* __restrict__ xyz3,
    const float* __restrict__ xyz4,
    int4* idx0, float4* w0, int4* idx1, float4* w1,
    int4* idx2, float4* w2, int4* idx3, float4* w3) {
    __shared__ float lds[(256 + 1) * 4 * 4];  // 4 segs x (S4max+1) x {x,y,z,|b|2}
    int bid = blockIdx.x;
    int S, logS4;
    const float *xf, *xc;
    int4* io; float4* wo;
    if (bid < 1024)      { S = 1024; logS4 = 8; xf = xyz0; xc = xyz1; io = idx3; wo = w3; }
    else if (bid < 1280) { bid -= 1024; S = 256; logS4 = 6; xf = xyz1; xc = xyz2; io = idx2; wo = w2; }
    else if (bid < 1344) { bid -= 1280; S = 64;  logS4 = 4; xf = xyz2; xc = xyz3; io = idx1; wo = w1; }
    else                 { bid -= 1344; S = 16;  logS4 = 2; xf = xyz3; xc = xyz4; io = idx0; wo = w0; }
    const int N = S << 2;
    const int lognb = logS4 - 2;              // nb = N/64 = S/16
    const int b = bid >> lognb;
    const int nblk = bid & ((1 << lognb) - 1);
    const int S4 = S >> 2;

    const float* cbase = xc + (size_t)b * S * 3;
    for (int j = threadIdx.x; j < S; j += 256) {
        float x = cbase[j * 3 + 0], y = cbase[j * 3 + 1], z = cbase[j * 3 + 2];
        int seg = j >> logS4, jj = j & (S4 - 1);
        float* p = lds + (size_t)(seg * (S4 + 1) + jj) * 4;
        p[0] = x; p[1] = y; p[2] = z; p[3] = x * x + y * y + z * z;
    }
    __syncthreads();
    const int t = threadIdx.x;
    const int sub = t & 3;
    const int n = nblk * 64 + (t >> 2);
    const float* fp = xf + ((size_t)b * N + n) * 3;
    const float ax = fp[0], ay = fp[1], az = fp[2];
    const float an2 = ax * ax + ay * ay + az * az;
    float d0 = 1e30f, d1 = 1e30f, d2 = 1e30f;
    int i0 = -1, i1 = -1, i2 = -1;
    const f32x4* seg4 = reinterpret_cast<const f32x4*>(lds) + sub * (S4 + 1);
    const int jbase = sub * S4;
#pragma unroll 4
    for (int k = 0; k < S4; ++k) {
        f32x4 c = seg4[k];
        float d = an2 + c[3] - 2.0f * (ax * c[0] + ay * c[1] + az * c[2]);
        int j = jbase + k;
        if (d < d2) {  // ascending j: strict < keeps earliest index on ties
            if (d < d1) {
                d2 = d1; i2 = i1;
                if (d < d0) { d1 = d0; i1 = i0; d0 = d; i0 = j; }
                else        { d1 = d;  i1 = j; }
            } else { d2 = d; i2 = j; }
        }
    }
#pragma unroll
    for (int r = 1; r <= 2; r <<= 1) {
        float e0 = __shfl_xor(d0, r), e1 = __shfl_xor(d1, r), e2 = __shfl_xor(d2, r);
        int   j0 = __shfl_xor(i0, r), j1 = __shfl_xor(i1, r), j2 = __shfl_xor(i2, r);
        float ed[3] = {e0, e1, e2};
        int   ej[3] = {j0, j1, j2};
#pragma unroll
        for (int m = 0; m < 3; ++m) {
            float d = ed[m]; int j = ej[m];
            if (d < d0 || (d == d0 && j < i0)) {
                d2 = d1; i2 = i1; d1 = d0; i1 = i0; d0 = d; i0 = j;
            } else if (d < d1 || (d == d1 && j < i1)) {
                d2 = d1; i2 = i1; d1 = d; i1 = j;
            } else if (d < d2 || (d == d2 && j < i2)) {
                d2 = d; i2 = j;
            }
        }
    }
    if (sub == 0) {
        float w0_ = 1.0f / (d0 + 1e-8f);
        float w1_ = 1.0f / (d1 + 1e-8f);
        float w2_ = 1.0f / (d2 + 1e-8f);
        float inv = 1.0f / (w0_ + w1_ + w2_);
        size_t o = (size_t)b * N + n;
        io[o] = make_int4(i0, i1, i2, 0);
        wo[o] = make_float4(w0_ * inv, w1_ * inv, w2_ * inv, 0.0f);
    }
}

// ===================== decode mega-kernel =====================
// Block = (batch, 8-channel out chunk). The chunk's lineage is a single
// source level; expand level-by-level entirely in LDS (4-channel f32x4
// planes), then final interp (idx3) -> d_out. No intermediates in HBM.

// Repack 8 rows of length P (row-major) into 2 planes of f32x4[P].
template <int P>
__device__ __forceinline__ void copy_planes(const float* __restrict__ src_rows,
                                            f32x4* dst, int t) {
    constexpr int P4 = P / 4;
    const f32x4* src = reinterpret_cast<const f32x4*>(src_rows);
    float* df = reinterpret_cast<float*>(dst);
    for (int e = t; e < 8 * P4; e += 256) {
        int c = e / P4;
        int s4 = e & (P4 - 1);
        f32x4 v = src[c * P4 + s4];
        int base = (((c >> 2) * P + s4 * 4) << 2) + (c & 3);
        df[base + 0] = v[0]; df[base + 4] = v[1];
        df[base + 8] = v[2]; df[base + 12] = v[3];
    }
}

// dst[2][PD] <- gather(src[2][PS]) via per-point 3-NN idx/w.
template <int PD, int PS>
__device__ __forceinline__ void expand(const f32x4* src, f32x4* dst,
                                       const int4* __restrict__ idxL,
                                       const f32x4* __restrict__ wL,
                                       int b, int t) {
    for (int e = t; e < 2 * PD; e += 256) {
        int p = (e >= PD) ? 1 : 0;
        int s = e - p * PD;
        int4 id = idxL[(size_t)b * PD + s];
        f32x4 ww = wL[(size_t)b * PD + s];
        const f32x4* sp = src + p * PS;
        dst[e] = ww[0] * sp[id.x] + ww[1] * sp[id.y] + ww[2] * sp[id.z];
    }
}

__global__ __launch_bounds__(256) void decode_kernel(
    const float* __restrict__ f0, const float* __restrict__ f1,
    const float* __restrict__ f2, const float* __restrict__ f3,
    const float* __restrict__ f4,
    const int4* __restrict__ idx0, const f32x4* __restrict__ w0,
    const int4* __restrict__ idx1, const f32x4* __restrict__ w1,
    const int4* __restrict__ idx2, const f32x4* __restrict__ w2,
    const int4* __restrict__ idx3, const f32x4* __restrict__ w3,
    float* __restrict__ out) {
    __shared__ f32x4 s3[2 * 1024];  // 32 KB
    __shared__ f32x4 s2[2 * 256];   // 8 KB
    __shared__ f32x4 s1[2 * 64];    // 2 KB
    __shared__ f32x4 s0[2 * 16];    // 0.5 KB
    const int b = blockIdx.x;
    const int c0 = blockIdx.y * 8;
    const int t = threadIdx.x;
    float* outb = out + ((size_t)b * 1984 + c0) * 4096;

    if (c0 < 64) {  // pure copy of f0 rows
        const f32x4* src = reinterpret_cast<const f32x4*>(f0 + ((size_t)b * 64 + c0) * 4096);
        f32x4* dst = reinterpret_cast<f32x4*>(outb);
        for (int i = t; i < 8 * 1024; i += 256) dst[i] = src[i];
        return;
    }
    const int cx = c0 - 64;  // x3 channel base, in [0,1920)
    if (cx < 128) {          // depth 1: source f1
        copy_planes<1024>(f1 + ((size_t)b * 128 + cx) * 1024, s3, t);
        __syncthreads();
    } else if (cx < 384) {   // depth 2: source f2
        copy_planes<256>(f2 + ((size_t)b * 256 + (cx - 128)) * 256, s2, t);
        __syncthreads();
        expand<1024, 256>(s2, s3, idx2, w2, b, t);
        __syncthreads();
    } else if (cx < 896) {   // depth 3: source f3
        copy_planes<64>(f3 + ((size_t)b * 512 + (cx - 384)) * 64, s1, t);
        __syncthreads();
        expand<256, 64>(s1, s2, idx1, w1, b, t);
        __syncthreads();
        expand<1024, 256>(s2, s3, idx2, w2, b, t);
        __syncthreads();
    } else {                 // depth 4: source f4
        copy_planes<16>(f4 + ((size_t)b * 1024 + (cx - 896)) * 16, s0, t);
        __syncthreads();
        expand<64, 16>(s0, s1, idx0, w0, b, t);
        __syncthreads();
        expand<256, 64>(s1, s2, idx1, w1, b, t);
        __syncthreads();
        expand<1024, 256>(s2, s3, idx2, w2, b, t);
        __syncthreads();
    }
    // final level: 4096 fine points via idx3/w3, f32x4 stores along n
    const int4* idxF = idx3 + (size_t)b * 4096;
    const f32x4* wF = w3 + (size_t)b * 4096;
    for (int it = 0; it < 4; ++it) {
        const int n0 = (it * 256 + t) * 4;
        int4 id[4]; f32x4 ww[4];
#pragma unroll
        for (int q = 0; q < 4; ++q) { id[q] = idxF[n0 + q]; ww[q] = wF[n0 + q]; }
#pragma unroll
        for (int p = 0; p < 2; ++p) {
            const f32x4* pl = s3 + p * 1024;
            f32x4 v[4];
#pragma unroll
            for (int q = 0; q < 4; ++q) {
                v[q] = ww[q][0] * pl[id[q].x] + ww[q][1] * pl[id[q].y]
                     + ww[q][2] * pl[id[q].z];
            }
            float* ob = outb + (size_t)(p * 4) * 4096 + n0;
#pragma unroll
            for (int j = 0; j < 4; ++j) {
                f32x4 st = {v[0][j], v[1][j], v[2][j], v[3][j]};
                *reinterpret_cast<f32x4*>(ob + (size_t)j * 4096) = st;
            }
        }
    }
}

extern "C" void kernel_launch(void* const* d_in, const int* in_sizes, int n_in,
                              void* d_out, int out_size, void* d_ws, size_t ws_size,
                              hipStream_t stream) {
    static const int xyzSz[5] = {16 * 4096 * 3, 16 * 1024 * 3, 16 * 256 * 3,
                                 16 * 64 * 3, 16 * 16 * 3};
    static const int fSz[5] = {16 * 64 * 4096, 16 * 128 * 1024, 16 * 256 * 256,
                               16 * 512 * 64, 16 * 1024 * 16};
    const float* xyz[5] = {nullptr, nullptr, nullptr, nullptr, nullptr};
    const float* f[5] = {nullptr, nullptr, nullptr, nullptr, nullptr};
    for (int i = 0; i < n_in; ++i) {
        for (int j = 0; j < 5; ++j) {
            if (in_sizes[i] == xyzSz[j] && !xyz[j]) { xyz[j] = (const float*)d_in[i]; goto next; }
            if (in_sizes[i] == fSz[j] && !f[j])     { f[j] = (const float*)d_in[i];  goto next; }
        }
    next:;
    }

    // ws layout (per-stage idx/w; ~2.7 MB total, L2-resident)
    char* ws = (char*)d_ws;
    int4*   idx3 = (int4*)(ws);                       // 16*4096*16 = 1 MiB
    float4* w3   = (float4*)(ws + (1u << 20));        // 1 MiB
    int4*   idx2 = (int4*)(ws + (2u << 20));          // 256 KiB
    float4* w2   = (float4*)(ws + (2u << 20) + 262144u);
    int4*   idx1 = (int4*)(ws + (2u << 20) + 524288u);   // 64 KiB
    float4* w1   = (float4*)(ws + (2u << 20) + 589824u);
    int4*   idx0 = (int4*)(ws + (2u << 20) + 655360u);   // 16 KiB
    float4* w0   = (float4*)(ws + (2u << 20) + 671744u);

    knn_all_kernel<<<1360, 256, 0, stream>>>(
        xyz[0], xyz[1], xyz[2], xyz[3], xyz[4],
        idx0, w0, idx1, w1, idx2, w2, idx3, w3);

    decode_kernel<<<dim3(B, 248), 256, 0, stream>>>(
        f[0], f[1], f[2], f[3], f[4],
        idx0, (const f32x4*)w0, idx1, (const f32x4*)w1,
        idx2, (const f32x4*)w2, idx3, (const f32x4*)w3,
        (float*)d_out);
}

// Round 4
// 126.186 us; speedup vs baseline: 5.1828x; 1.1938x over previous
//
#include <hip/hip_runtime.h>

#define B 16
typedef float f32x4 __attribute__((ext_vector_type(4)));

// ===================== fused 4-stage 3-NN + f0 copy =====================
// Blocks [0,1024): stage3 knn; [1024,1280): stage2; [1280,1344): stage1;
// [1344,1360): stage0; [1360,1488): f0 -> out copy (needs no idx, overlaps
// HBM traffic under the knn compute).
__global__ __launch_bounds__(256) void knn_all_kernel(
    const float* __restrict__ xyz0, const float* __restrict__ xyz1,
    const float* __restrict__ xyz2, const float* __restrict__ xyz3,
    const float* __restrict__ xyz4, const float* __restrict__ f0,
    float* __restrict__ out,
    int4* idx0, float4* w0, int4* idx1, float4* w1,
    int4* idx2, float4* w2, int4* idx3, float4* w3) {
    __shared__ float lds[(256 + 1) * 4 * 4];  // 4 segs x (S4max+1) x {x,y,z,|b|2}
    int bid = blockIdx.x;
    if (bid >= 1360) {  // f0 copy: chunk of 8 channels, nontemporal streaming
        bid -= 1360;
        const int b = bid >> 3;
        const int c0 = (bid & 7) * 8;
        const f32x4* src = reinterpret_cast<const f32x4*>(f0 + ((size_t)b * 64 + c0) * 4096);
        f32x4* dst = reinterpret_cast<f32x4*>(out + ((size_t)b * 1984 + c0) * 4096);
        for (int i = threadIdx.x; i < 8 * 1024; i += 256) {
            __builtin_nontemporal_store(__builtin_nontemporal_load(src + i), dst + i);
        }
        return;
    }
    int S, logS4;
    const float *xf, *xc;
    int4* io; float4* wo;
    if (bid < 1024)      { S = 1024; logS4 = 8; xf = xyz0; xc = xyz1; io = idx3; wo = w3; }
    else if (bid < 1280) { bid -= 1024; S = 256; logS4 = 6; xf = xyz1; xc = xyz2; io = idx2; wo = w2; }
    else if (bid < 1344) { bid -= 1280; S = 64;  logS4 = 4; xf = xyz2; xc = xyz3; io = idx1; wo = w1; }
    else                 { bid -= 1344; S = 16;  logS4 = 2; xf = xyz3; xc = xyz4; io = idx0; wo = w0; }
    const int N = S << 2;
    const int lognb = logS4 - 2;              // nb = N/64 = S/16
    const int b = bid >> lognb;
    const int nblk = bid & ((1 << lognb) - 1);
    const int S4 = S >> 2;

    const float* cbase = xc + (size_t)b * S * 3;
    for (int j = threadIdx.x; j < S; j += 256) {
        float x = cbase[j * 3 + 0], y = cbase[j * 3 + 1], z = cbase[j * 3 + 2];
        int seg = j >> logS4, jj = j & (S4 - 1);
        float* p = lds + (size_t)(seg * (S4 + 1) + jj) * 4;
        p[0] = x; p[1] = y; p[2] = z; p[3] = x * x + y * y + z * z;
    }
    __syncthreads();
    const int t = threadIdx.x;
    const int sub = t & 3;
    const int n = nblk * 64 + (t >> 2);
    const float* fp = xf + ((size_t)b * N + n) * 3;
    const float ax = fp[0], ay = fp[1], az = fp[2];
    const float an2 = ax * ax + ay * ay + az * az;
    float d0 = 1e30f, d1 = 1e30f, d2 = 1e30f;
    int i0 = -1, i1 = -1, i2 = -1;
    const f32x4* seg4 = reinterpret_cast<const f32x4*>(lds) + sub * (S4 + 1);
    const int jbase = sub * S4;
#pragma unroll 4
    for (int k = 0; k < S4; ++k) {
        f32x4 c = seg4[k];
        float d = an2 + c[3] - 2.0f * (ax * c[0] + ay * c[1] + az * c[2]);
        int j = jbase + k;
        if (d < d2) {  // ascending j: strict < keeps earliest index on ties
            if (d < d1) {
                d2 = d1; i2 = i1;
                if (d < d0) { d1 = d0; i1 = i0; d0 = d; i0 = j; }
                else        { d1 = d;  i1 = j; }
            } else { d2 = d; i2 = j; }
        }
    }
#pragma unroll
    for (int r = 1; r <= 2; r <<= 1) {
        float e0 = __shfl_xor(d0, r), e1 = __shfl_xor(d1, r), e2 = __shfl_xor(d2, r);
        int   j0 = __shfl_xor(i0, r), j1 = __shfl_xor(i1, r), j2 = __shfl_xor(i2, r);
        float ed[3] = {e0, e1, e2};
        int   ej[3] = {j0, j1, j2};
#pragma unroll
        for (int m = 0; m < 3; ++m) {
            float d = ed[m]; int j = ej[m];
            if (d < d0 || (d == d0 && j < i0)) {
                d2 = d1; i2 = i1; d1 = d0; i1 = i0; d0 = d; i0 = j;
            } else if (d < d1 || (d == d1 && j < i1)) {
                d2 = d1; i2 = i1; d1 = d; i1 = j;
            } else if (d < d2 || (d == d2 && j < i2)) {
                d2 = d; i2 = j;
            }
        }
    }
    if (sub == 0) {
        float w0_ = 1.0f / (d0 + 1e-8f);
        float w1_ = 1.0f / (d1 + 1e-8f);
        float w2_ = 1.0f / (d2 + 1e-8f);
        float inv = 1.0f / (w0_ + w1_ + w2_);
        size_t o = (size_t)b * N + n;
        io[o] = make_int4(i0, i1, i2, 0);
        wo[o] = make_float4(w0_ * inv, w1_ * inv, w2_ * inv, 0.0f);
    }
}

// ===================== decode mega-kernel =====================
// Block = (batch, 8-channel chunk of the interpolated region). Lineage is a
// single source level; expand level-by-level in LDS (4-channel f32x4 planes),
// then final interp (idx3) streamed to d_out with nontemporal stores.
// LDS union (exactly 40 KB -> 4 blocks/CU):
//   s3 = buf[0..2048)       (32 KB, final 2 planes x 1024)
//   s2 = buf[2048..2560)    (8 KB)
//   s1 = buf[0..128)        (aliases s3 area; dead before s3 is written)
//   s0 = buf[128..160)      (aliases s3 area; dead before s1 consumed it)

template <int P>
__device__ __forceinline__ void copy_planes(const float* __restrict__ src_rows,
                                            f32x4* dst, int t) {
    constexpr int P4 = P / 4;
    const f32x4* src = reinterpret_cast<const f32x4*>(src_rows);
    float* df = reinterpret_cast<float*>(dst);
    for (int e = t; e < 8 * P4; e += 256) {
        int c = e / P4;
        int s4 = e & (P4 - 1);
        f32x4 v = src[c * P4 + s4];
        int base = (((c >> 2) * P + s4 * 4) << 2) + (c & 3);
        df[base + 0] = v[0]; df[base + 4] = v[1];
        df[base + 8] = v[2]; df[base + 12] = v[3];
    }
}

template <int PD, int PS>
__device__ __forceinline__ void expand(const f32x4* src, f32x4* dst,
                                       const int4* __restrict__ idxL,
                                       const f32x4* __restrict__ wL,
                                       int b, int t) {
    for (int e = t; e < 2 * PD; e += 256) {
        int p = (e >= PD) ? 1 : 0;
        int s = e - p * PD;
        int4 id = idxL[(size_t)b * PD + s];
        f32x4 ww = wL[(size_t)b * PD + s];
        const f32x4* sp = src + p * PS;
        dst[e] = ww[0] * sp[id.x] + ww[1] * sp[id.y] + ww[2] * sp[id.z];
    }
}

__global__ __launch_bounds__(256) void decode_kernel(
    const float* __restrict__ f1, const float* __restrict__ f2,
    const float* __restrict__ f3, const float* __restrict__ f4,
    const int4* __restrict__ idx0, const f32x4* __restrict__ w0,
    const int4* __restrict__ idx1, const f32x4* __restrict__ w1,
    const int4* __restrict__ idx2, const f32x4* __restrict__ w2,
    const int4* __restrict__ idx3, const f32x4* __restrict__ w3,
    float* __restrict__ out) {
    __shared__ f32x4 buf[2560];  // 40 KB exactly
    f32x4* s3 = buf;
    f32x4* s2 = buf + 2048;
    f32x4* s1 = buf;        // alias (dead before s3 written)
    f32x4* s0 = buf + 128;  // alias
    const int b = blockIdx.x;
    // heavy-first order: y=0 -> deepest chunk (cx largest)
    const int cx = (239 - blockIdx.y) * 8;  // [0,1920), interpolated channels
    const int t = threadIdx.x;
    float* outb = out + ((size_t)b * 1984 + 64 + cx) * 4096;

    if (cx < 128) {          // depth 1: source f1
        copy_planes<1024>(f1 + ((size_t)b * 128 + cx) * 1024, s3, t);
        __syncthreads();
    } else if (cx < 384) {   // depth 2: source f2
        copy_planes<256>(f2 + ((size_t)b * 256 + (cx - 128)) * 256, s2, t);
        __syncthreads();
        expand<1024, 256>(s2, s3, idx2, w2, b, t);
        __syncthreads();
    } else if (cx < 896) {   // depth 3: source f3
        copy_planes<64>(f3 + ((size_t)b * 512 + (cx - 384)) * 64, s1, t);
        __syncthreads();
        expand<256, 64>(s1, s2, idx1, w1, b, t);
        __syncthreads();
        expand<1024, 256>(s2, s3, idx2, w2, b, t);
        __syncthreads();
    } else {                 // depth 4: source f4
        copy_planes<16>(f4 + ((size_t)b * 1024 + (cx - 896)) * 16, s0, t);
        __syncthreads();
        expand<64, 16>(s0, s1, idx0, w0, b, t);   // s0 (buf+128) -> s1 (buf+0)
        __syncthreads();
        expand<256, 64>(s1, s2, idx1, w1, b, t);
        __syncthreads();
        expand<1024, 256>(s2, s3, idx2, w2, b, t);
        __syncthreads();
    }
    // final level: 4096 fine points via idx3/w3, f32x4 nontemporal stores
    const int4* idxF = idx3 + (size_t)b * 4096;
    const f32x4* wF = w3 + (size_t)b * 4096;
#pragma unroll 2
    for (int it = 0; it < 4; ++it) {
        const int n0 = (it * 256 + t) * 4;
        int4 id[4]; f32x4 ww[4];
#pragma unroll
        for (int q = 0; q < 4; ++q) { id[q] = idxF[n0 + q]; ww[q] = wF[n0 + q]; }
#pragma unroll
        for (int p = 0; p < 2; ++p) {
            const f32x4* pl = s3 + p * 1024;
            f32x4 v[4];
#pragma unroll
            for (int q = 0; q < 4; ++q) {
                v[q] = ww[q][0] * pl[id[q].x] + ww[q][1] * pl[id[q].y]
                     + ww[q][2] * pl[id[q].z];
            }
            float* ob = outb + (size_t)(p * 4) * 4096 + n0;
#pragma unroll
            for (int j = 0; j < 4; ++j) {
                f32x4 st = {v[0][j], v[1][j], v[2][j], v[3][j]};
                __builtin_nontemporal_store(st, reinterpret_cast<f32x4*>(ob + (size_t)j * 4096));
            }
        }
    }
}

extern "C" void kernel_launch(void* const* d_in, const int* in_sizes, int n_in,
                              void* d_out, int out_size, void* d_ws, size_t ws_size,
                              hipStream_t stream) {
    static const int xyzSz[5] = {16 * 4096 * 3, 16 * 1024 * 3, 16 * 256 * 3,
                                 16 * 64 * 3, 16 * 16 * 3};
    static const int fSz[5] = {16 * 64 * 4096, 16 * 128 * 1024, 16 * 256 * 256,
                               16 * 512 * 64, 16 * 1024 * 16};
    const float* xyz[5] = {nullptr, nullptr, nullptr, nullptr, nullptr};
    const float* f[5] = {nullptr, nullptr, nullptr, nullptr, nullptr};
    for (int i = 0; i < n_in; ++i) {
        for (int j = 0; j < 5; ++j) {
            if (in_sizes[i] == xyzSz[j] && !xyz[j]) { xyz[j] = (const float*)d_in[i]; goto next; }
            if (in_sizes[i] == fSz[j] && !f[j])     { f[j] = (const float*)d_in[i];  goto next; }
        }
    next:;
    }

    // ws layout (per-stage idx/w; ~2.7 MB, L2-resident)
    char* ws = (char*)d_ws;
    int4*   idx3 = (int4*)(ws);                       // 1 MiB
    float4* w3   = (float4*)(ws + (1u << 20));        // 1 MiB
    int4*   idx2 = (int4*)(ws + (2u << 20));          // 256 KiB
    float4* w2   = (float4*)(ws + (2u << 20) + 262144u);
    int4*   idx1 = (int4*)(ws + (2u << 20) + 524288u);   // 64 KiB
    float4* w1   = (float4*)(ws + (2u << 20) + 589824u);
    int4*   idx0 = (int4*)(ws + (2u << 20) + 655360u);   // 16 KiB
    float4* w0   = (float4*)(ws + (2u << 20) + 671744u);

    knn_all_kernel<<<1488, 256, 0, stream>>>(
        xyz[0], xyz[1], xyz[2], xyz[3], xyz[4], f[0], (float*)d_out,
        idx0, w0, idx1, w1, idx2, w2, idx3, w3);

    decode_kernel<<<dim3(B, 240), 256, 0, stream>>>(
        f[1], f[2], f[3], f[4],
        idx0, (const f32x4*)w0, idx1, (const f32x4*)w1,
        idx2, (const f32x4*)w2, idx3, (const f32x4*)w3,
        (float*)d_out);
}